// Round 6
// baseline (1024.102 us; speedup 1.0000x reference)
//
#include <hip/hip_runtime.h>

typedef __attribute__((ext_vector_type(8))) short bf16x8;
typedef __attribute__((ext_vector_type(4))) short s16x4;
typedef __attribute__((ext_vector_type(4))) float f32x4;

#define MFMA16(a,b,c) __builtin_amdgcn_mfma_f32_16x16x32_bf16((a),(b),(c),0,0,0)

__device__ __forceinline__ unsigned short f2bf(float f) {
  unsigned int u = __float_as_uint(f);
  return (unsigned short)((u + 0x7fffu + ((u >> 16) & 1u)) >> 16);  // RNE
}

__device__ __forceinline__ void gload16(const void* g, void* l) {
  __builtin_amdgcn_global_load_lds((const __attribute__((address_space(1))) void*)g,
                                   (__attribute__((address_space(3))) void*)l, 16, 0, 0);
}

// ---- f32 -> bf16 bulk convert ----
__global__ __launch_bounds__(256) void cvt_bf16(const float* __restrict__ in,
                                                unsigned short* __restrict__ out, int n8) {
  for (int i = blockIdx.x * 256 + threadIdx.x; i < n8; i += gridDim.x * 256) {
    float4 a = ((const float4*)in)[2 * i];
    float4 b = ((const float4*)in)[2 * i + 1];
    s16x4 p0, p1;
    p0[0] = f2bf(a.x); p0[1] = f2bf(a.y); p0[2] = f2bf(a.z); p0[3] = f2bf(a.w);
    p1[0] = f2bf(b.x); p1[1] = f2bf(b.y); p1[2] = f2bf(b.z); p1[3] = f2bf(b.w);
    ((s16x4*)out)[2 * i] = p0;
    ((s16x4*)out)[2 * i + 1] = p1;
  }
}

// ---- W[K][N] f32 -> Wt[N][K] bf16 ----
__global__ __launch_bounds__(256) void tcvt(const float* __restrict__ W,
                                            unsigned short* __restrict__ Wt, int K, int N) {
  __shared__ float t[32][33];
  const int n0 = blockIdx.x * 32, k0 = blockIdx.y * 32;
  const int c = threadIdx.x & 31, r8 = threadIdx.x >> 5;
#pragma unroll
  for (int p = 0; p < 4; ++p) {
    int r = r8 + p * 8;
    t[r][c] = W[(size_t)(k0 + r) * N + n0 + c];
  }
  __syncthreads();
#pragma unroll
  for (int p = 0; p < 4; ++p) {
    int r = r8 + p * 8;
    Wt[(size_t)(n0 + r) * K + k0 + c] = f2bf(t[c][r]);
  }
}

// ---- bf16 GEMM: C = A[M,1024] @ Bt[N,1024]^T ----
__global__ __launch_bounds__(256) void proj_gemm(
    const unsigned short* __restrict__ A, const unsigned short* __restrict__ Bt,
    unsigned short* __restrict__ C, int N, int mode, float scale)
{
  __shared__ __align__(16) unsigned short As[2][4096];
  __shared__ __align__(16) unsigned short Bs[2][4096];
  const int tid = threadIdx.x, lane = tid & 63, w = tid >> 6;
  const int wr = w >> 1, wc = w & 1;
  const int lrow = lane & 15, lg = lane >> 4;
  const size_t bm = (size_t)blockIdx.x * 128;
  const size_t bn = (size_t)blockIdx.y * 128;
  const int rl = lane >> 2, cq = lane & 3;

  auto stage = [&](int kt, int buf) {
#pragma unroll
    for (int u = 0; u < 2; ++u) {
      int row = w * 32 + u * 16 + rl;
      gload16(A  + (bm + row) * 1024 + kt * 32 + cq * 8, &As[buf][(w * 32 + u * 16) * 32]);
      gload16(Bt + (bn + row) * 1024 + kt * 32 + cq * 8, &Bs[buf][(w * 32 + u * 16) * 32]);
    }
  };

  f32x4 acc[4][4] = {};
  stage(0, 0);
  __syncthreads();

  for (int kt = 0; kt < 32; ++kt) {
    const int cur = kt & 1;
    if (kt + 1 < 32) stage(kt + 1, cur ^ 1);
    bf16x8 af[4], bfr[4];
#pragma unroll
    for (int i = 0; i < 4; ++i)
      af[i] = *(const bf16x8*)&As[cur][(wr * 64 + i * 16 + lrow) * 32 + lg * 8];
#pragma unroll
    for (int j = 0; j < 4; ++j)
      bfr[j] = *(const bf16x8*)&Bs[cur][(wc * 64 + j * 16 + lrow) * 32 + lg * 8];
    __builtin_amdgcn_s_setprio(1);
#pragma unroll
    for (int i = 0; i < 4; ++i)
#pragma unroll
      for (int j = 0; j < 4; ++j)
        acc[i][j] = MFMA16(af[i], bfr[j], acc[i][j]);
    __builtin_amdgcn_s_setprio(0);
    __syncthreads();
  }

  const int orow0 = blockIdx.x * 128 + wr * 64;
  const int ocol0 = blockIdx.y * 128 + wc * 64;
  if (mode == 0) {
#pragma unroll
    for (int i = 0; i < 4; ++i)
#pragma unroll
      for (int j = 0; j < 4; ++j) {
        int col = ocol0 + j * 16 + lrow;
#pragma unroll
        for (int r = 0; r < 4; ++r) {
          int row = orow0 + i * 16 + lg * 4 + r;
          C[(size_t)row * N + col] = f2bf(acc[i][j][r] * scale);
        }
      }
  } else {
#pragma unroll
    for (int i = 0; i < 4; ++i) {
      int m0 = orow0 + i * 16 + lg * 4;
      int bb = m0 >> 11, t = m0 & 2047;
      int tg = t >> 5, tin = t & 31;
#pragma unroll
      for (int j = 0; j < 4; ++j) {
        int e = ocol0 + j * 16 + lrow;
        int eg = e >> 4;
        s16x4 pk;
#pragma unroll
        for (int r = 0; r < 4; ++r) pk[r] = (short)f2bf(acc[i][j][r]);
        *(s16x4*)(C + (size_t)bb * 2097152 + ((size_t)eg * 64 + tg) * 512 + lrow * 32 + tin) = pk;
      }
    }
  }
}

// ---- Flash attention: V-split x2 for 2 blocks/CU; in-reg softmax; 3 raw barriers ----
// Block handles 64 q-rows x 512 out-cols. acc[4][4]=64 VGPR. LDS ~74.7KB.
__global__ __launch_bounds__(512, 4) void attn_kernel(
    const unsigned short* __restrict__ Q,   // [16][2048][256] bf16 (pre-scaled)
    const unsigned short* __restrict__ Kk,  // [16][2048][256] bf16
    const unsigned short* __restrict__ Vp,  // packed [16][64][64][16][32] bf16
    const float* __restrict__ X, float* __restrict__ Out)
{
  __shared__ __align__(16) unsigned short Ks[2][64 * 256];  // 64KB, XOR-swizzled content
  __shared__ __align__(16) unsigned short Ps[64 * 72];      // 9KB
  __shared__ __align__(8) float PMax[64][2];
  __shared__ float al_s[64];
  __shared__ __align__(8) float Lp[64][2];

  // bid: [2:0]=xcd, slot=bid>>3: [6]=batch-within-xcd, [5:1]=q-tile, [0]=v-half
  const int bid = blockIdx.x;
  const int xcd = bid & 7, slot = bid >> 3;
  const int b  = xcd * 2 + (slot >> 6);
  const int q0 = ((slot >> 1) & 31) * 64;
  const int vh = slot & 1;

  const int tid = threadIdx.x, lane = tid & 63, w = tid >> 6;
  const int lrow = lane & 15, lg = lane >> 4;
  const int si = w & 3, cg = w >> 2;        // S: rows si*16..+16, cols cg*32..+32
  const int myrow0 = si * 16 + lg * 4;

  bf16x8 qf[8];
  const unsigned short* qb = Q + ((size_t)b * 2048 + q0 + si * 16 + lrow) * 256;
#pragma unroll
  for (int ks = 0; ks < 8; ++ks) qf[ks] = *(const bf16x8*)(qb + ks * 32 + lg * 8);

  const unsigned short* kb = Kk + (size_t)b * 2048 * 256;
  const unsigned short* vb = Vp + (size_t)b * 2097152;

  const int srl = lane >> 5, scc = (lane & 31) * 16;
  auto stageK = [&](int tile, int buf) {
#pragma unroll
    for (int is = 0; is < 4; ++is) {
      int row = w * 8 + is * 2 + srl;
      int cb = scc ^ ((row & 7) << 4);
      gload16((const char*)kb + (size_t)(tile * 64 + row) * 512 + cb,
              (char*)&Ks[buf][0] + (w * 8 + is * 2) * 512);
    }
  };

  const int r0 = cg * 32 + lrow;
  const int rx = (r0 & 7) << 4;

  float m_reg[4], l_reg[4];
#pragma unroll
  for (int r = 0; r < 4; ++r) { m_reg[r] = -3.0e38f; l_reg[r] = 0.f; }

  f32x4 acc[4][4] = {};  // out rows 16i+(lg*4+r), cols vh*512 + w*64 + 16n + lrow

  // ---- prologue ----
  stageK(0, 0);
  asm volatile("s_waitcnt vmcnt(0)" ::: "memory");
  __builtin_amdgcn_s_barrier();

  for (int t = 0; t < 32; ++t) {
    const int cur = t & 1;
    // ---- P1: QK^T in registers + max partials ----
    f32x4 s0v = {}, s1v = {};
    {
      const char* kbase = (const char*)&Ks[cur][0];
      __builtin_amdgcn_s_setprio(1);
#pragma unroll
      for (int ks = 0; ks < 8; ++ks) {
        bf16x8 k0 = *(const bf16x8*)(kbase + r0 * 512 + ((ks * 64 + lg * 16) ^ rx));
        bf16x8 k1 = *(const bf16x8*)(kbase + (r0 + 16) * 512 + ((ks * 64 + lg * 16) ^ rx));
        s0v = MFMA16(qf[ks], k0, s0v);
        s1v = MFMA16(qf[ks], k1, s1v);
      }
      __builtin_amdgcn_s_setprio(0);
    }
    {
      float pm[4];
#pragma unroll
      for (int r = 0; r < 4; ++r) pm[r] = fmaxf(s0v[r], s1v[r]);
#pragma unroll
      for (int r = 0; r < 4; ++r) {
        pm[r] = fmaxf(pm[r], __shfl_xor(pm[r], 1));
        pm[r] = fmaxf(pm[r], __shfl_xor(pm[r], 2));
        pm[r] = fmaxf(pm[r], __shfl_xor(pm[r], 4));
        pm[r] = fmaxf(pm[r], __shfl_xor(pm[r], 8));
      }
      if (lrow == 0) {
#pragma unroll
        for (int r = 0; r < 4; ++r) PMax[myrow0 + r][cg] = pm[r];
      }
    }
    asm volatile("s_waitcnt lgkmcnt(0)" ::: "memory");
    __builtin_amdgcn_s_barrier();            // bar1: PMax visible

    // ---- P1b: finish softmax in-reg; write Ps/al_s; issue K(t+1) stage ----
    {
      float p0[4], p1[4], rs[4], al[4];
#pragma unroll
      for (int r = 0; r < 4; ++r) {
        float2 pp = *(const float2*)&PMax[myrow0 + r][0];
        float mn = fmaxf(m_reg[r], fmaxf(pp.x, pp.y));
        al[r] = __expf(m_reg[r] - mn);
        m_reg[r] = mn;
        p0[r] = __expf(s0v[r] - mn);
        p1[r] = __expf(s1v[r] - mn);
        rs[r] = p0[r] + p1[r];
      }
#pragma unroll
      for (int r = 0; r < 4; ++r) {
        rs[r] += __shfl_xor(rs[r], 1);
        rs[r] += __shfl_xor(rs[r], 2);
        rs[r] += __shfl_xor(rs[r], 4);
        rs[r] += __shfl_xor(rs[r], 8);
        l_reg[r] = l_reg[r] * al[r] + rs[r];
      }
      if (cg == 0 && lrow == 0) {
#pragma unroll
        for (int r = 0; r < 4; ++r) al_s[myrow0 + r] = al[r];
      }
#pragma unroll
      for (int r = 0; r < 4; ++r) {
        Ps[(myrow0 + r) * 72 + cg * 32 + lrow]      = f2bf(p0[r]);
        Ps[(myrow0 + r) * 72 + cg * 32 + 16 + lrow] = f2bf(p1[r]);
      }
    }
    if (t + 1 < 32) stageK(t + 1, cur ^ 1);
    asm volatile("s_waitcnt lgkmcnt(0)" ::: "memory");
    __builtin_amdgcn_s_barrier();            // bar2: Ps/al_s visible

    // ---- P3: rescale + PV (V from L2-resident packed tiles, pairs) ----
    {
#pragma unroll
      for (int i = 0; i < 4; ++i) {
        f32x4 a4;
#pragma unroll
        for (int r = 0; r < 4; ++r) a4[r] = al_s[i * 16 + lg * 4 + r];
#pragma unroll
        for (int n = 0; n < 4; ++n) acc[i][n] *= a4;
      }
#pragma unroll
      for (int kk = 0; kk < 2; ++kk) {
        bf16x8 pf[4];
#pragma unroll
        for (int i = 0; i < 4; ++i)
          pf[i] = *(const bf16x8*)&Ps[(i * 16 + lrow) * 72 + kk * 32 + lg * 8];
#pragma unroll
        for (int np = 0; np < 2; ++np) {     // pairs: cap register peak
          bf16x8 va = *(const bf16x8*)(vb + ((size_t)((vh * 32 + w * 4 + np * 2) * 64)
                                        + (t * 2 + kk)) * 512 + lrow * 32 + lg * 8);
          bf16x8 vc = *(const bf16x8*)(vb + ((size_t)((vh * 32 + w * 4 + np * 2 + 1) * 64)
                                        + (t * 2 + kk)) * 512 + lrow * 32 + lg * 8);
          __builtin_amdgcn_s_setprio(1);
#pragma unroll
          for (int i = 0; i < 4; ++i) acc[i][np * 2]     = MFMA16(pf[i], va, acc[i][np * 2]);
#pragma unroll
          for (int i = 0; i < 4; ++i) acc[i][np * 2 + 1] = MFMA16(pf[i], vc, acc[i][np * 2 + 1]);
          __builtin_amdgcn_s_setprio(0);
        }
      }
    }
    __builtin_amdgcn_s_barrier();            // bar3: dbuf safety (stage retired via V waits)
  }

  // ---- epilogue: combine l partials, out = acc/l + x ----
  if (lrow == 0) {
#pragma unroll
    for (int r = 0; r < 4; ++r) Lp[myrow0 + r][cg] = l_reg[r];
  }
  __syncthreads();
#pragma unroll
  for (int i = 0; i < 4; ++i) {
#pragma unroll
    for (int r = 0; r < 4; ++r) {
      int row = i * 16 + lg * 4 + r;
      float2 lp = *(const float2*)&Lp[row][0];
      float inv = 1.0f / (lp.x + lp.y);
      const float* xr = X + ((size_t)b * 2048 + q0 + row) * 1024;
      float* orp = Out + ((size_t)b * 2048 + q0 + row) * 1024;
#pragma unroll
      for (int n = 0; n < 4; ++n) {
        int col = vh * 512 + w * 64 + n * 16 + lrow;
        orp[col] = acc[i][n][r] * inv + xr[col];
      }
    }
  }
}

extern "C" void kernel_launch(void* const* d_in, const int* in_sizes, int n_in,
                              void* d_out, int out_size, void* d_ws, size_t ws_size,
                              hipStream_t stream) {
  (void)in_sizes; (void)n_in; (void)out_size; (void)ws_size;
  const float* x  = (const float*)d_in[0];
  const float* y  = (const float*)d_in[1];
  const float* Wq = (const float*)d_in[2];
  const float* Wk = (const float*)d_in[3];
  const float* Wv = (const float*)d_in[4];
  float* out = (float*)d_out;

  unsigned short* xb = (unsigned short*)d_out;
  unsigned short* yb = xb + (size_t)16 * 2048 * 1024;

  unsigned short* Wqt = (unsigned short*)d_ws;
  unsigned short* Wkt = Wqt + (size_t)256 * 1024;
  unsigned short* Wvt = Wkt + (size_t)256 * 1024;
  unsigned short* qws = Wvt + (size_t)1024 * 1024;
  unsigned short* kws = qws + (size_t)16 * 2048 * 256;
  unsigned short* vpw = kws + (size_t)16 * 2048 * 256;

  const int n8 = (16 * 2048 * 1024) / 8;
  cvt_bf16<<<2048, 256, 0, stream>>>(x, xb, n8);
  cvt_bf16<<<2048, 256, 0, stream>>>(y, yb, n8);
  tcvt<<<dim3(8, 32),  256, 0, stream>>>(Wq, Wqt, 1024, 256);
  tcvt<<<dim3(8, 32),  256, 0, stream>>>(Wk, Wkt, 1024, 256);
  tcvt<<<dim3(32, 32), 256, 0, stream>>>(Wv, Wvt, 1024, 1024);

  proj_gemm<<<dim3(256, 2), 256, 0, stream>>>(xb, Wqt, qws, 256, 0, 0.03125f);
  proj_gemm<<<dim3(256, 2), 256, 0, stream>>>(yb, Wkt, kws, 256, 0, 1.0f);
  proj_gemm<<<dim3(256, 8), 256, 0, stream>>>(yb, Wvt, vpw, 1024, 2, 1.0f);

  attn_kernel<<<1024, 512, 0, stream>>>(qws, kws, vpw, x, out);
}

// Round 8
// 620.905 us; speedup vs baseline: 1.6494x; 1.6494x over previous
//
#include <hip/hip_runtime.h>

typedef __attribute__((ext_vector_type(8))) short bf16x8;
typedef __attribute__((ext_vector_type(4))) short s16x4;
typedef __attribute__((ext_vector_type(4))) float f32x4;

#define MFMA16(a,b,c) __builtin_amdgcn_mfma_f32_16x16x32_bf16((a),(b),(c),0,0,0)

__device__ __forceinline__ unsigned short f2bf(float f) {
  unsigned int u = __float_as_uint(f);
  return (unsigned short)((u + 0x7fffu + ((u >> 16) & 1u)) >> 16);  // RNE
}
__device__ __forceinline__ float bf2f(unsigned short u) {
  return __uint_as_float(((unsigned int)u) << 16);
}

__device__ __forceinline__ void gload16(const void* g, void* l) {
  __builtin_amdgcn_global_load_lds((const __attribute__((address_space(1))) void*)g,
                                   (__attribute__((address_space(3))) void*)l, 16, 0, 0);
}

// ---- f32 -> bf16 bulk convert ----
__global__ __launch_bounds__(256) void cvt_bf16(const float* __restrict__ in,
                                                unsigned short* __restrict__ out, int n8) {
  for (int i = blockIdx.x * 256 + threadIdx.x; i < n8; i += gridDim.x * 256) {
    float4 a = ((const float4*)in)[2 * i];
    float4 b = ((const float4*)in)[2 * i + 1];
    s16x4 p0, p1;
    p0[0] = f2bf(a.x); p0[1] = f2bf(a.y); p0[2] = f2bf(a.z); p0[3] = f2bf(a.w);
    p1[0] = f2bf(b.x); p1[1] = f2bf(b.y); p1[2] = f2bf(b.z); p1[3] = f2bf(b.w);
    ((s16x4*)out)[2 * i] = p0;
    ((s16x4*)out)[2 * i + 1] = p1;
  }
}

// ---- W[K][N] f32 -> Wt[N][K] bf16 ----
__global__ __launch_bounds__(256) void tcvt(const float* __restrict__ W,
                                            unsigned short* __restrict__ Wt, int K, int N) {
  __shared__ float t[32][33];
  const int n0 = blockIdx.x * 32, k0 = blockIdx.y * 32;
  const int c = threadIdx.x & 31, r8 = threadIdx.x >> 5;
#pragma unroll
  for (int p = 0; p < 4; ++p) {
    int r = r8 + p * 8;
    t[r][c] = W[(size_t)(k0 + r) * N + n0 + c];
  }
  __syncthreads();
#pragma unroll
  for (int p = 0; p < 4; ++p) {
    int r = r8 + p * 8;
    Wt[(size_t)(n0 + r) * K + k0 + c] = f2bf(t[c][r]);
  }
}

// ---- projection GEMM: C = A[M,1024] @ Bt[N,1024]^T (bf16 in/out) ----
// mode 0: C row-major [M][N] scaled.  mode 2: Vt[b][e][t] transpose per batch.
__global__ __launch_bounds__(256) void proj_gemm(
    const unsigned short* __restrict__ A, const unsigned short* __restrict__ Bt,
    unsigned short* __restrict__ C, int N, int mode, float scale)
{
  __shared__ __align__(16) unsigned short As[2][4096];
  __shared__ __align__(16) unsigned short Bs[2][4096];
  const int tid = threadIdx.x, lane = tid & 63, w = tid >> 6;
  const int wr = w >> 1, wc = w & 1;
  const int lrow = lane & 15, lg = lane >> 4;
  const size_t bm = (size_t)blockIdx.x * 128;
  const size_t bn = (size_t)blockIdx.y * 128;
  const int rl = lane >> 2, cq = lane & 3;

  auto stage = [&](int kt, int buf) {
#pragma unroll
    for (int u = 0; u < 2; ++u) {
      int row = w * 32 + u * 16 + rl;
      gload16(A  + (bm + row) * 1024 + kt * 32 + cq * 8, &As[buf][(w * 32 + u * 16) * 32]);
      gload16(Bt + (bn + row) * 1024 + kt * 32 + cq * 8, &Bs[buf][(w * 32 + u * 16) * 32]);
    }
  };

  f32x4 acc[4][4] = {};
  stage(0, 0);
  __syncthreads();

  for (int kt = 0; kt < 32; ++kt) {
    const int cur = kt & 1;
    if (kt + 1 < 32) stage(kt + 1, cur ^ 1);
    bf16x8 af[4], bfr[4];
#pragma unroll
    for (int i = 0; i < 4; ++i)
      af[i] = *(const bf16x8*)&As[cur][(wr * 64 + i * 16 + lrow) * 32 + lg * 8];
#pragma unroll
    for (int j = 0; j < 4; ++j)
      bfr[j] = *(const bf16x8*)&Bs[cur][(wc * 64 + j * 16 + lrow) * 32 + lg * 8];
    __builtin_amdgcn_s_setprio(1);
#pragma unroll
    for (int i = 0; i < 4; ++i)
#pragma unroll
      for (int j = 0; j < 4; ++j)
        acc[i][j] = MFMA16(af[i], bfr[j], acc[i][j]);
    __builtin_amdgcn_s_setprio(0);
    __syncthreads();
  }

  const int orow0 = blockIdx.x * 128 + wr * 64;
  const int ocol0 = blockIdx.y * 128 + wc * 64;
  if (mode == 0) {
#pragma unroll
    for (int i = 0; i < 4; ++i)
#pragma unroll
      for (int j = 0; j < 4; ++j) {
        int col = ocol0 + j * 16 + lrow;
#pragma unroll
        for (int r = 0; r < 4; ++r) {
          int row = orow0 + i * 16 + lg * 4 + r;
          C[(size_t)row * N + col] = f2bf(acc[i][j][r] * scale);
        }
      }
  } else {
#pragma unroll
    for (int i = 0; i < 4; ++i) {
      int m0 = orow0 + i * 16 + lg * 4;   // 4 consecutive t within one batch
      int bb = m0 >> 11, t = m0 & 2047;
#pragma unroll
      for (int j = 0; j < 4; ++j) {
        int e = ocol0 + j * 16 + lrow;
        s16x4 pk;
#pragma unroll
        for (int r = 0; r < 4; ++r) pk[r] = (short)f2bf(acc[i][j][r]);
        *(s16x4*)(C + (size_t)bb * 2097152 + (size_t)e * 2048 + t) = pk;
      }
    }
  }
}

// ---- S = q @ k^T (batched, K=256, bf16 out). grid = nb*256 blocks ----
__global__ __launch_bounds__(256) void sgemm_kernel(
    const unsigned short* __restrict__ Qm,  // [16][2048][256] (pre-scaled)
    const unsigned short* __restrict__ Km,  // [16][2048][256]
    unsigned short* __restrict__ Sp,        // [nb][2048][2048]
    int b0)
{
  __shared__ __align__(16) unsigned short As[2][4096];
  __shared__ __align__(16) unsigned short Bs[2][4096];
  const int bloc = blockIdx.x >> 8, tile = blockIdx.x & 255;
  const int mtile = tile >> 4, ntile = tile & 15;
  const int gb = b0 + bloc;
  const unsigned short* A  = Qm + (size_t)gb * 2048 * 256;
  const unsigned short* Bt = Km + (size_t)gb * 2048 * 256;
  const int tid = threadIdx.x, lane = tid & 63, w = tid >> 6;
  const int wr = w >> 1, wc = w & 1;
  const int lrow = lane & 15, lg = lane >> 4;
  const size_t bm = (size_t)mtile * 128, bn = (size_t)ntile * 128;
  const int rl = lane >> 2, cq = lane & 3;

  auto stage = [&](int kt, int buf) {
#pragma unroll
    for (int u = 0; u < 2; ++u) {
      int row = w * 32 + u * 16 + rl;
      gload16(A  + (bm + row) * 256 + kt * 32 + cq * 8, &As[buf][(w * 32 + u * 16) * 32]);
      gload16(Bt + (bn + row) * 256 + kt * 32 + cq * 8, &Bs[buf][(w * 32 + u * 16) * 32]);
    }
  };

  f32x4 acc[4][4] = {};
  stage(0, 0);
  __syncthreads();
  for (int kt = 0; kt < 8; ++kt) {
    const int cur = kt & 1;
    if (kt + 1 < 8) stage(kt + 1, cur ^ 1);
    bf16x8 af[4], bfr[4];
#pragma unroll
    for (int i = 0; i < 4; ++i)
      af[i] = *(const bf16x8*)&As[cur][(wr * 64 + i * 16 + lrow) * 32 + lg * 8];
#pragma unroll
    for (int j = 0; j < 4; ++j)
      bfr[j] = *(const bf16x8*)&Bs[cur][(wc * 64 + j * 16 + lrow) * 32 + lg * 8];
    __builtin_amdgcn_s_setprio(1);
#pragma unroll
    for (int i = 0; i < 4; ++i)
#pragma unroll
      for (int j = 0; j < 4; ++j)
        acc[i][j] = MFMA16(af[i], bfr[j], acc[i][j]);
    __builtin_amdgcn_s_setprio(0);
    __syncthreads();
  }

  unsigned short* Cp = Sp + (size_t)bloc * 2048 * 2048;
  const int orow0 = mtile * 128 + wr * 64;
  const int ocol0 = ntile * 128 + wc * 64;
#pragma unroll
  for (int i = 0; i < 4; ++i)
#pragma unroll
    for (int j = 0; j < 4; ++j) {
      int col = ocol0 + j * 16 + lrow;
#pragma unroll
      for (int r = 0; r < 4; ++r) {
        int row = orow0 + i * 16 + lg * 4 + r;
        Cp[(size_t)row * 2048 + col] = f2bf(acc[i][j][r]);
      }
    }
}

// ---- softmax in-place over rows of Sp (normalized P out). 1 wave / row ----
__global__ __launch_bounds__(256) void softmax_kernel(unsigned short* __restrict__ Sp) {
  const int row = blockIdx.x * 4 + (threadIdx.x >> 6);
  const int lane = threadIdx.x & 63;
  unsigned short* rp = Sp + (size_t)row * 2048;
  bf16x8 raw[4];
#pragma unroll
  for (int c = 0; c < 4; ++c) raw[c] = *(const bf16x8*)(rp + c * 512 + lane * 8);
  float v[32];
#pragma unroll
  for (int c = 0; c < 4; ++c)
#pragma unroll
    for (int j = 0; j < 8; ++j) v[c * 8 + j] = bf2f((unsigned short)raw[c][j]);
  float mx = v[0];
#pragma unroll
  for (int j = 1; j < 32; ++j) mx = fmaxf(mx, v[j]);
  mx = fmaxf(mx, __shfl_xor(mx, 1));
  mx = fmaxf(mx, __shfl_xor(mx, 2));
  mx = fmaxf(mx, __shfl_xor(mx, 4));
  mx = fmaxf(mx, __shfl_xor(mx, 8));
  mx = fmaxf(mx, __shfl_xor(mx, 16));
  mx = fmaxf(mx, __shfl_xor(mx, 32));
  float sum = 0.f;
#pragma unroll
  for (int j = 0; j < 32; ++j) { v[j] = __expf(v[j] - mx); sum += v[j]; }
  sum += __shfl_xor(sum, 1);
  sum += __shfl_xor(sum, 2);
  sum += __shfl_xor(sum, 4);
  sum += __shfl_xor(sum, 8);
  sum += __shfl_xor(sum, 16);
  sum += __shfl_xor(sum, 32);
  float inv = 1.0f / sum;
#pragma unroll
  for (int c = 0; c < 4; ++c) {
    bf16x8 pk;
#pragma unroll
    for (int j = 0; j < 8; ++j) pk[j] = (short)f2bf(v[c * 8 + j] * inv);
    *(bf16x8*)(rp + c * 512 + lane * 8) = pk;
  }
}

// ---- Out = P @ Vt^T + X (batched, K=2048, f32 out). grid = t*nb + bloc ----
__global__ __launch_bounds__(256) void pvgemm_kernel(
    const unsigned short* __restrict__ Pp,  // [nb][2048][2048] normalized
    const unsigned short* __restrict__ Vt,  // [16][1024][2048]
    const float* __restrict__ X, float* __restrict__ Out,
    int b0, int nb)
{
  __shared__ __align__(16) unsigned short As[2][4096];
  __shared__ __align__(16) unsigned short Bs[2][4096];
  // bid = t*nb + bloc  ->  batch pinned to XCD when nb%8==0 (bid%8 == bloc%8)
  const int bloc = blockIdx.x % nb, t = blockIdx.x / nb;
  const int mtile = t >> 3, ntile = t & 7;   // n-inner: A-panel L2 reuse
  const int gb = b0 + bloc;
  const unsigned short* A  = Pp + (size_t)bloc * 2048 * 2048;
  const unsigned short* Bt = Vt + (size_t)gb * 1024 * 2048;
  const int tid = threadIdx.x, lane = tid & 63, w = tid >> 6;
  const int wr = w >> 1, wc = w & 1;
  const int lrow = lane & 15, lg = lane >> 4;
  const size_t bm = (size_t)mtile * 128, bn = (size_t)ntile * 128;
  const int rl = lane >> 2, cq = lane & 3;

  auto stage = [&](int kt, int buf) {
#pragma unroll
    for (int u = 0; u < 2; ++u) {
      int row = w * 32 + u * 16 + rl;
      gload16(A  + (bm + row) * 2048 + kt * 32 + cq * 8, &As[buf][(w * 32 + u * 16) * 32]);
      gload16(Bt + (bn + row) * 2048 + kt * 32 + cq * 8, &Bs[buf][(w * 32 + u * 16) * 32]);
    }
  };

  f32x4 acc[4][4] = {};
  stage(0, 0);
  __syncthreads();
  for (int kt = 0; kt < 64; ++kt) {
    const int cur = kt & 1;
    if (kt + 1 < 64) stage(kt + 1, cur ^ 1);
    bf16x8 af[4], bfr[4];
#pragma unroll
    for (int i = 0; i < 4; ++i)
      af[i] = *(const bf16x8*)&As[cur][(wr * 64 + i * 16 + lrow) * 32 + lg * 8];
#pragma unroll
    for (int j = 0; j < 4; ++j)
      bfr[j] = *(const bf16x8*)&Bs[cur][(wc * 64 + j * 16 + lrow) * 32 + lg * 8];
    __builtin_amdgcn_s_setprio(1);
#pragma unroll
    for (int i = 0; i < 4; ++i)
#pragma unroll
      for (int j = 0; j < 4; ++j)
        acc[i][j] = MFMA16(af[i], bfr[j], acc[i][j]);
    __builtin_amdgcn_s_setprio(0);
    __syncthreads();
  }

  const int orow0 = mtile * 128 + wr * 64;
  const int ocol0 = ntile * 128 + wc * 64;
#pragma unroll
  for (int i = 0; i < 4; ++i)
#pragma unroll
    for (int r = 0; r < 4; ++r) {
      int row = orow0 + i * 16 + lg * 4 + r;
      const float* xr = X   + ((size_t)gb * 2048 + row) * 1024;
      float*      orp = Out + ((size_t)gb * 2048 + row) * 1024;
#pragma unroll
      for (int j = 0; j < 4; ++j) {
        int col = ocol0 + j * 16 + lrow;
        orp[col] = acc[i][j][r] + xr[col];
      }
    }
}

extern "C" void kernel_launch(void* const* d_in, const int* in_sizes, int n_in,
                              void* d_out, int out_size, void* d_ws, size_t ws_size,
                              hipStream_t stream) {
  (void)in_sizes; (void)n_in; (void)out_size;
  const float* x  = (const float*)d_in[0];
  const float* y  = (const float*)d_in[1];
  const float* Wq = (const float*)d_in[2];
  const float* Wk = (const float*)d_in[3];
  const float* Wv = (const float*)d_in[4];
  float* out = (float*)d_out;

  // bf16 copies of x,y live in d_out during projections (overwritten by pvgemm later)
  unsigned short* xb = (unsigned short*)d_out;
  unsigned short* yb = xb + (size_t)16 * 2048 * 1024;

  // ws (bf16 elems): Wqt | Wkt | Wvt | q | k | Vt | S/P
  unsigned short* Wqt = (unsigned short*)d_ws;
  unsigned short* Wkt = Wqt + (size_t)256 * 1024;
  unsigned short* Wvt = Wkt + (size_t)256 * 1024;
  unsigned short* qws = Wvt + (size_t)1024 * 1024;
  unsigned short* kws = qws + (size_t)16 * 2048 * 256;
  unsigned short* vtw = kws + (size_t)16 * 2048 * 256;
  unsigned short* Sp  = vtw + (size_t)16 * 1024 * 2048;

  const size_t fixed_bytes = (size_t)(Sp - Wqt) * 2;
  const size_t s_batch_bytes = (size_t)2048 * 2048 * 2;
  int nb = 1;
  if      (ws_size >= fixed_bytes + 16 * s_batch_bytes) nb = 16;
  else if (ws_size >= fixed_bytes + 8  * s_batch_bytes) nb = 8;
  else if (ws_size >= fixed_bytes + 4  * s_batch_bytes) nb = 4;
  else if (ws_size >= fixed_bytes + 2  * s_batch_bytes) nb = 2;
  else nb = 1;

  const int n8 = (16 * 2048 * 1024) / 8;
  cvt_bf16<<<2048, 256, 0, stream>>>(x, xb, n8);
  cvt_bf16<<<2048, 256, 0, stream>>>(y, yb, n8);
  tcvt<<<dim3(8, 32),  256, 0, stream>>>(Wq, Wqt, 1024, 256);
  tcvt<<<dim3(8, 32),  256, 0, stream>>>(Wk, Wkt, 1024, 256);
  tcvt<<<dim3(32, 32), 256, 0, stream>>>(Wv, Wvt, 1024, 1024);

  // q scaled by 1/sqrt(OUT_DIM) = 1/32
  proj_gemm<<<dim3(256, 2), 256, 0, stream>>>(xb, Wqt, qws, 256, 0, 0.03125f);
  proj_gemm<<<dim3(256, 2), 256, 0, stream>>>(yb, Wkt, kws, 256, 0, 1.0f);
  proj_gemm<<<dim3(256, 8), 256, 0, stream>>>(yb, Wvt, vtw, 1024, 2, 1.0f);

  for (int b0 = 0; b0 < 16; b0 += nb) {
    sgemm_kernel<<<nb * 256, 256, 0, stream>>>(qws, kws, Sp, b0);
    softmax_kernel<<<nb * 512, 256, 0, stream>>>(Sp);
    pvgemm_kernel<<<nb * 128, 256, 0, stream>>>(Sp, vtw, x, out, b0, nb);
  }
}

// Round 9
// 540.322 us; speedup vs baseline: 1.8954x; 1.1491x over previous
//
#include <hip/hip_runtime.h>

typedef __attribute__((ext_vector_type(8))) short bf16x8;
typedef __attribute__((ext_vector_type(4))) short s16x4;
typedef __attribute__((ext_vector_type(4))) float f32x4;

#define MFMA16(a,b,c) __builtin_amdgcn_mfma_f32_16x16x32_bf16((a),(b),(c),0,0,0)

__device__ __forceinline__ unsigned short f2bf(float f) {
  unsigned int u = __float_as_uint(f);
  return (unsigned short)((u + 0x7fffu + ((u >> 16) & 1u)) >> 16);  // RNE
}
__device__ __forceinline__ float bf2f(unsigned short u) {
  return __uint_as_float(((unsigned int)u) << 16);
}

__device__ __forceinline__ void gload16(const void* g, void* l) {
  __builtin_amdgcn_global_load_lds((const __attribute__((address_space(1))) void*)g,
                                   (__attribute__((address_space(3))) void*)l, 16, 0, 0);
}

// ---- f32 -> bf16 bulk convert ----
__global__ __launch_bounds__(256) void cvt_bf16(const float* __restrict__ in,
                                                unsigned short* __restrict__ out, int n8) {
  for (int i = blockIdx.x * 256 + threadIdx.x; i < n8; i += gridDim.x * 256) {
    float4 a = ((const float4*)in)[2 * i];
    float4 b = ((const float4*)in)[2 * i + 1];
    s16x4 p0, p1;
    p0[0] = f2bf(a.x); p0[1] = f2bf(a.y); p0[2] = f2bf(a.z); p0[3] = f2bf(a.w);
    p1[0] = f2bf(b.x); p1[1] = f2bf(b.y); p1[2] = f2bf(b.z); p1[3] = f2bf(b.w);
    ((s16x4*)out)[2 * i] = p0;
    ((s16x4*)out)[2 * i + 1] = p1;
  }
}

// ---- W[K][N] f32 -> Wt[N][K] bf16 ----
__global__ __launch_bounds__(256) void tcvt(const float* __restrict__ W,
                                            unsigned short* __restrict__ Wt, int K, int N) {
  __shared__ float t[32][33];
  const int n0 = blockIdx.x * 32, k0 = blockIdx.y * 32;
  const int c = threadIdx.x & 31, r8 = threadIdx.x >> 5;
#pragma unroll
  for (int p = 0; p < 4; ++p) {
    int r = r8 + p * 8;
    t[r][c] = W[(size_t)(k0 + r) * N + n0 + c];
  }
  __syncthreads();
#pragma unroll
  for (int p = 0; p < 4; ++p) {
    int r = r8 + p * 8;
    Wt[(size_t)(n0 + r) * K + k0 + c] = f2bf(t[c][r]);
  }
}

// ---- projection GEMM (m97-style, 128x128): C = A[M,1024] @ Bt[N,1024]^T ----
__global__ __launch_bounds__(256) void proj_gemm(
    const unsigned short* __restrict__ A, const unsigned short* __restrict__ Bt,
    unsigned short* __restrict__ C, int N, int mode, float scale)
{
  __shared__ __align__(16) unsigned short As[2][4096];
  __shared__ __align__(16) unsigned short Bs[2][4096];
  const int tid = threadIdx.x, lane = tid & 63, w = tid >> 6;
  const int wr = w >> 1, wc = w & 1;
  const int lrow = lane & 15, lg = lane >> 4;
  const size_t bm = (size_t)blockIdx.x * 128;
  const size_t bn = (size_t)blockIdx.y * 128;
  const int rl = lane >> 2, cq = lane & 3;

  auto stage = [&](int kt, int buf) {
#pragma unroll
    for (int u = 0; u < 2; ++u) {
      int row = w * 32 + u * 16 + rl;
      gload16(A  + (bm + row) * 1024 + kt * 32 + cq * 8, &As[buf][(w * 32 + u * 16) * 32]);
      gload16(Bt + (bn + row) * 1024 + kt * 32 + cq * 8, &Bs[buf][(w * 32 + u * 16) * 32]);
    }
  };

  f32x4 acc[4][4] = {};
  stage(0, 0);
  __syncthreads();

  for (int kt = 0; kt < 32; ++kt) {
    const int cur = kt & 1;
    if (kt + 1 < 32) stage(kt + 1, cur ^ 1);
    bf16x8 af[4], bfr[4];
#pragma unroll
    for (int i = 0; i < 4; ++i)
      af[i] = *(const bf16x8*)&As[cur][(wr * 64 + i * 16 + lrow) * 32 + lg * 8];
#pragma unroll
    for (int j = 0; j < 4; ++j)
      bfr[j] = *(const bf16x8*)&Bs[cur][(wc * 64 + j * 16 + lrow) * 32 + lg * 8];
    __builtin_amdgcn_s_setprio(1);
#pragma unroll
    for (int i = 0; i < 4; ++i)
#pragma unroll
      for (int j = 0; j < 4; ++j)
        acc[i][j] = MFMA16(af[i], bfr[j], acc[i][j]);
    __builtin_amdgcn_s_setprio(0);
    __syncthreads();
  }

  const int orow0 = blockIdx.x * 128 + wr * 64;
  const int ocol0 = blockIdx.y * 128 + wc * 64;
  if (mode == 0) {
#pragma unroll
    for (int i = 0; i < 4; ++i)
#pragma unroll
      for (int j = 0; j < 4; ++j) {
        int col = ocol0 + j * 16 + lrow;
#pragma unroll
        for (int r = 0; r < 4; ++r) {
          int row = orow0 + i * 16 + lg * 4 + r;
          C[(size_t)row * N + col] = f2bf(acc[i][j][r] * scale);
        }
      }
  } else {
#pragma unroll
    for (int i = 0; i < 4; ++i) {
      int m0 = orow0 + i * 16 + lg * 4;   // 4 consecutive t within one batch
      int bb = m0 >> 11, t = m0 & 2047;
#pragma unroll
      for (int j = 0; j < 4; ++j) {
        int e = ocol0 + j * 16 + lrow;
        s16x4 pk;
#pragma unroll
        for (int r = 0; r < 4; ++r) pk[r] = (short)f2bf(acc[i][j][r]);
        *(s16x4*)(C + (size_t)bb * 2097152 + (size_t)e * 2048 + t) = pk;
      }
    }
  }
}

// ======================================================================
// Deep-pipelined 256x256 GEMM core: BK=32, tri-buffered LDS (96KB),
// 1 raw barrier + 1 counted vmcnt per K-tile, no vmcnt(0) drain in loop.
// Race-free by construction: tile j+2 staged into slot (j+2)%3 == (j-1)%3,
// whose reads completed before this tile's barrier.
// Swizzle: 16B-chunk q stored at q ^ ((row>>1)&3)  (both sides, involution).
// ======================================================================

// ---- S = q @ k^T (batched, K=256, bf16 out). grid = nb*64 ----
__global__ __launch_bounds__(512) void sgemm2_kernel(
    const unsigned short* __restrict__ Qm,  // [16][2048][256] (pre-scaled)
    const unsigned short* __restrict__ Km,  // [16][2048][256]
    unsigned short* __restrict__ Sp,        // [nb][2048][2048]
    int b0, int nb)
{
  __shared__ __align__(16) unsigned short lds[49152];  // 3 x (A 8192 | B 8192)
  const int bloc = blockIdx.x % nb, t = blockIdx.x / nb;
  const int mtile = t >> 3, ntile = t & 7;
  const int gb = b0 + bloc;
  const unsigned short* Ag = Qm + (size_t)gb * 2048 * 256;
  const unsigned short* Bg = Km + (size_t)gb * 2048 * 256;
  const int K = 256, NT = 8;
  const size_t bm = (size_t)mtile * 256, bn = (size_t)ntile * 256;

  const int tid = threadIdx.x, lane = tid & 63, w = tid >> 6;
  const int wm = w >> 2, wn = w & 3;
  const int lrow = lane & 15, lg = lane >> 4;

  auto stageT = [&](int jt, int slot) {
#pragma unroll
    for (int i = 0; i < 2; ++i) {
      int c = tid + 512 * i; int row = c >> 2; int ql = (c & 3) ^ ((row >> 1) & 3);
      gload16(Ag + (bm + row) * K + jt * 32 + ql * 8, &lds[slot * 16384 + c * 8]);
    }
#pragma unroll
    for (int i = 0; i < 2; ++i) {
      int c = tid + 512 * i; int row = c >> 2; int ql = (c & 3) ^ ((row >> 1) & 3);
      gload16(Bg + (bn + row) * K + jt * 32 + ql * 8, &lds[slot * 16384 + 8192 + c * 8]);
    }
  };

  f32x4 acc[8][4] = {};
  stageT(0, 0); stageT(1, 1);

  for (int jt = 0; jt < NT; ++jt) {
    const int slot = jt % 3;
    if (jt < NT - 1) asm volatile("s_waitcnt vmcnt(4)" ::: "memory");
    else             asm volatile("s_waitcnt vmcnt(0)" ::: "memory");
    __builtin_amdgcn_sched_barrier(0);
    __builtin_amdgcn_s_barrier();
    __builtin_amdgcn_sched_barrier(0);
    if (jt + 2 < NT) stageT(jt + 2, (jt + 2) % 3);
    const unsigned short* Ab = &lds[slot * 16384];
    const unsigned short* Bb = &lds[slot * 16384 + 8192];
    bf16x8 bfr[4];
#pragma unroll
    for (int nf = 0; nf < 4; ++nf) {
      int brow = wn * 64 + nf * 16 + lrow;
      bfr[nf] = *(const bf16x8*)&Bb[brow * 32 + ((lg ^ ((brow >> 1) & 3)) * 8)];
    }
    __builtin_amdgcn_s_setprio(1);
#pragma unroll
    for (int mf = 0; mf < 8; ++mf) {
      int arow = wm * 128 + mf * 16 + lrow;
      bf16x8 a = *(const bf16x8*)&Ab[arow * 32 + ((lg ^ ((arow >> 1) & 3)) * 8)];
#pragma unroll
      for (int nf = 0; nf < 4; ++nf)
        acc[mf][nf] = MFMA16(a, bfr[nf], acc[mf][nf]);
    }
    __builtin_amdgcn_s_setprio(0);
  }

  unsigned short* Cp = Sp + (size_t)bloc * 2048 * 2048;
#pragma unroll
  for (int mf = 0; mf < 8; ++mf)
#pragma unroll
    for (int r = 0; r < 4; ++r) {
      int row = (int)bm + wm * 128 + mf * 16 + lg * 4 + r;
#pragma unroll
      for (int nf = 0; nf < 4; ++nf) {
        int col = (int)bn + wn * 64 + nf * 16 + lrow;
        Cp[(size_t)row * 2048 + col] = f2bf(acc[mf][nf][r]);
      }
    }
}

// ---- softmax in-place over rows of Sp (normalized P out). 1 wave / row ----
__global__ __launch_bounds__(256) void softmax_kernel(unsigned short* __restrict__ Sp) {
  const int row = blockIdx.x * 4 + (threadIdx.x >> 6);
  const int lane = threadIdx.x & 63;
  unsigned short* rp = Sp + (size_t)row * 2048;
  bf16x8 raw[4];
#pragma unroll
  for (int c = 0; c < 4; ++c) raw[c] = *(const bf16x8*)(rp + c * 512 + lane * 8);
  float v[32];
#pragma unroll
  for (int c = 0; c < 4; ++c)
#pragma unroll
    for (int j = 0; j < 8; ++j) v[c * 8 + j] = bf2f((unsigned short)raw[c][j]);
  float mx = v[0];
#pragma unroll
  for (int j = 1; j < 32; ++j) mx = fmaxf(mx, v[j]);
  mx = fmaxf(mx, __shfl_xor(mx, 1));
  mx = fmaxf(mx, __shfl_xor(mx, 2));
  mx = fmaxf(mx, __shfl_xor(mx, 4));
  mx = fmaxf(mx, __shfl_xor(mx, 8));
  mx = fmaxf(mx, __shfl_xor(mx, 16));
  mx = fmaxf(mx, __shfl_xor(mx, 32));
  float sum = 0.f;
#pragma unroll
  for (int j = 0; j < 32; ++j) { v[j] = __expf(v[j] - mx); sum += v[j]; }
  sum += __shfl_xor(sum, 1);
  sum += __shfl_xor(sum, 2);
  sum += __shfl_xor(sum, 4);
  sum += __shfl_xor(sum, 8);
  sum += __shfl_xor(sum, 16);
  sum += __shfl_xor(sum, 32);
  float inv = 1.0f / sum;
#pragma unroll
  for (int c = 0; c < 4; ++c) {
    bf16x8 pk;
#pragma unroll
    for (int j = 0; j < 8; ++j) pk[j] = (short)f2bf(v[c * 8 + j] * inv);
    *(bf16x8*)(rp + c * 512 + lane * 8) = pk;
  }
}

// ---- Out = P @ Vt^T + X (batched, K=2048, f32 out). grid = nb*32 ----
__global__ __launch_bounds__(512) void pvgemm2_kernel(
    const unsigned short* __restrict__ Pp,  // [nb][2048][2048] normalized
    const unsigned short* __restrict__ Vt,  // [16][1024][2048]
    const float* __restrict__ X, float* __restrict__ Out,
    int b0, int nb)
{
  __shared__ __align__(16) unsigned short lds[49152];
  const int bloc = blockIdx.x % nb, t = blockIdx.x / nb;
  const int mtile = t >> 2, ntile = t & 3;
  const int gb = b0 + bloc;
  const unsigned short* Ag = Pp + (size_t)bloc * 2048 * 2048;
  const unsigned short* Bg = Vt + (size_t)gb * 1024 * 2048;
  const int K = 2048, NT = 64;
  const size_t bm = (size_t)mtile * 256, bn = (size_t)ntile * 256;

  const int tid = threadIdx.x, lane = tid & 63, w = tid >> 6;
  const int wm = w >> 2, wn = w & 3;
  const int lrow = lane & 15, lg = lane >> 4;

  auto stageT = [&](int jt, int slot) {
#pragma unroll
    for (int i = 0; i < 2; ++i) {
      int c = tid + 512 * i; int row = c >> 2; int ql = (c & 3) ^ ((row >> 1) & 3);
      gload16(Ag + (bm + row) * K + jt * 32 + ql * 8, &lds[slot * 16384 + c * 8]);
    }
#pragma unroll
    for (int i = 0; i < 2; ++i) {
      int c = tid + 512 * i; int row = c >> 2; int ql = (c & 3) ^ ((row >> 1) & 3);
      gload16(Bg + (bn + row) * K + jt * 32 + ql * 8, &lds[slot * 16384 + 8192 + c * 8]);
    }
  };

  f32x4 acc[8][4] = {};
  stageT(0, 0); stageT(1, 1);

  for (int jt = 0; jt < NT; ++jt) {
    const int slot = jt % 3;
    if (jt < NT - 1) asm volatile("s_waitcnt vmcnt(4)" ::: "memory");
    else             asm volatile("s_waitcnt vmcnt(0)" ::: "memory");
    __builtin_amdgcn_sched_barrier(0);
    __builtin_amdgcn_s_barrier();
    __builtin_amdgcn_sched_barrier(0);
    if (jt + 2 < NT) stageT(jt + 2, (jt + 2) % 3);
    const unsigned short* Ab = &lds[slot * 16384];
    const unsigned short* Bb = &lds[slot * 16384 + 8192];
    bf16x8 bfr[4];
#pragma unroll
    for (int nf = 0; nf < 4; ++nf) {
      int brow = wn * 64 + nf * 16 + lrow;
      bfr[nf] = *(const bf16x8*)&Bb[brow * 32 + ((lg ^ ((brow >> 1) & 3)) * 8)];
    }
    __builtin_amdgcn_s_setprio(1);
#pragma unroll
    for (int mf = 0; mf < 8; ++mf) {
      int arow = wm * 128 + mf * 16 + lrow;
      bf16x8 a = *(const bf16x8*)&Ab[arow * 32 + ((lg ^ ((arow >> 1) & 3)) * 8)];
#pragma unroll
      for (int nf = 0; nf < 4; ++nf)
        acc[mf][nf] = MFMA16(a, bfr[nf], acc[mf][nf]);
    }
    __builtin_amdgcn_s_setprio(0);
  }

#pragma unroll
  for (int mf = 0; mf < 8; ++mf)
#pragma unroll
    for (int r = 0; r < 4; ++r) {
      int row = (int)bm + wm * 128 + mf * 16 + lg * 4 + r;
      const float* xr = X   + ((size_t)gb * 2048 + row) * 1024;
      float*      orp = Out + ((size_t)gb * 2048 + row) * 1024;
#pragma unroll
      for (int nf = 0; nf < 4; ++nf) {
        int col = (int)bn + wn * 64 + nf * 16 + lrow;
        orp[col] = acc[mf][nf][r] + xr[col];
      }
    }
}

extern "C" void kernel_launch(void* const* d_in, const int* in_sizes, int n_in,
                              void* d_out, int out_size, void* d_ws, size_t ws_size,
                              hipStream_t stream) {
  (void)in_sizes; (void)n_in; (void)out_size;
  const float* x  = (const float*)d_in[0];
  const float* y  = (const float*)d_in[1];
  const float* Wq = (const float*)d_in[2];
  const float* Wk = (const float*)d_in[3];
  const float* Wv = (const float*)d_in[4];
  float* out = (float*)d_out;

  // bf16 copies of x,y live in d_out during projections (overwritten by pvgemm later)
  unsigned short* xb = (unsigned short*)d_out;
  unsigned short* yb = xb + (size_t)16 * 2048 * 1024;

  // ws (bf16 elems): Wqt | Wkt | Wvt | q | k | Vt | S/P
  unsigned short* Wqt = (unsigned short*)d_ws;
  unsigned short* Wkt = Wqt + (size_t)256 * 1024;
  unsigned short* Wvt = Wkt + (size_t)256 * 1024;
  unsigned short* qws = Wvt + (size_t)1024 * 1024;
  unsigned short* kws = qws + (size_t)16 * 2048 * 256;
  unsigned short* vtw = kws + (size_t)16 * 2048 * 256;
  unsigned short* Sp  = vtw + (size_t)16 * 1024 * 2048;

  const size_t fixed_bytes = (size_t)(Sp - Wqt) * 2;
  const size_t s_batch_bytes = (size_t)2048 * 2048 * 2;
  int nb = 1;
  if      (ws_size >= fixed_bytes + 16 * s_batch_bytes) nb = 16;
  else if (ws_size >= fixed_bytes + 8  * s_batch_bytes) nb = 8;
  else if (ws_size >= fixed_bytes + 4  * s_batch_bytes) nb = 4;
  else if (ws_size >= fixed_bytes + 2  * s_batch_bytes) nb = 2;
  else nb = 1;

  const int n8 = (16 * 2048 * 1024) / 8;
  cvt_bf16<<<2048, 256, 0, stream>>>(x, xb, n8);
  cvt_bf16<<<2048, 256, 0, stream>>>(y, yb, n8);
  tcvt<<<dim3(8, 32),  256, 0, stream>>>(Wq, Wqt, 1024, 256);
  tcvt<<<dim3(8, 32),  256, 0, stream>>>(Wk, Wkt, 1024, 256);
  tcvt<<<dim3(32, 32), 256, 0, stream>>>(Wv, Wvt, 1024, 1024);

  // q scaled by 1/sqrt(OUT_DIM) = 1/32
  proj_gemm<<<dim3(256, 2), 256, 0, stream>>>(xb, Wqt, qws, 256, 0, 0.03125f);
  proj_gemm<<<dim3(256, 2), 256, 0, stream>>>(yb, Wkt, kws, 256, 0, 1.0f);
  proj_gemm<<<dim3(256, 8), 256, 0, stream>>>(yb, Wvt, vtw, 1024, 2, 1.0f);

  for (int b0 = 0; b0 < 16; b0 += nb) {
    sgemm2_kernel<<<nb * 64, 512, 0, stream>>>(qws, kws, Sp, b0, nb);
    softmax_kernel<<<nb * 512, 256, 0, stream>>>(Sp);
    pvgemm2_kernel<<<nb * 32, 512, 0, stream>>>(Sp, vtw, x, out, b0, nb);
  }
}

// Round 10
// 532.948 us; speedup vs baseline: 1.9216x; 1.0138x over previous
//
#include <hip/hip_runtime.h>

typedef __attribute__((ext_vector_type(8))) short bf16x8;
typedef __attribute__((ext_vector_type(4))) short s16x4;
typedef __attribute__((ext_vector_type(4))) float f32x4;

#define MFMA16(a,b,c) __builtin_amdgcn_mfma_f32_16x16x32_bf16((a),(b),(c),0,0,0)

__device__ __forceinline__ unsigned short f2bf(float f) {
  unsigned int u = __float_as_uint(f);
  return (unsigned short)((u + 0x7fffu + ((u >> 16) & 1u)) >> 16);  // RNE
}
__device__ __forceinline__ float bf2f(unsigned short u) {
  return __uint_as_float(((unsigned int)u) << 16);
}

__device__ __forceinline__ void gload16(const void* g, void* l) {
  __builtin_amdgcn_global_load_lds((const __attribute__((address_space(1))) void*)g,
                                   (__attribute__((address_space(3))) void*)l, 16, 0, 0);
}

// ---- f32 -> bf16 bulk convert ----
__global__ __launch_bounds__(256) void cvt_bf16(const float* __restrict__ in,
                                                unsigned short* __restrict__ out, int n8) {
  for (int i = blockIdx.x * 256 + threadIdx.x; i < n8; i += gridDim.x * 256) {
    float4 a = ((const float4*)in)[2 * i];
    float4 b = ((const float4*)in)[2 * i + 1];
    s16x4 p0, p1;
    p0[0] = f2bf(a.x); p0[1] = f2bf(a.y); p0[2] = f2bf(a.z); p0[3] = f2bf(a.w);
    p1[0] = f2bf(b.x); p1[1] = f2bf(b.y); p1[2] = f2bf(b.z); p1[3] = f2bf(b.w);
    ((s16x4*)out)[2 * i] = p0;
    ((s16x4*)out)[2 * i + 1] = p1;
  }
}

// ---- W[K][N] f32 -> Wt[N][K] bf16 ----
__global__ __launch_bounds__(256) void tcvt(const float* __restrict__ W,
                                            unsigned short* __restrict__ Wt, int K, int N) {
  __shared__ float t[32][33];
  const int n0 = blockIdx.x * 32, k0 = blockIdx.y * 32;
  const int c = threadIdx.x & 31, r8 = threadIdx.x >> 5;
#pragma unroll
  for (int p = 0; p < 4; ++p) {
    int r = r8 + p * 8;
    t[r][c] = W[(size_t)(k0 + r) * N + n0 + c];
  }
  __syncthreads();
#pragma unroll
  for (int p = 0; p < 4; ++p) {
    int r = r8 + p * 8;
    Wt[(size_t)(n0 + r) * K + k0 + c] = f2bf(t[c][r]);
  }
}

// ---- projection GEMM (m97-style, 128x128): C = A[M,1024] @ Bt[N,1024]^T ----
__global__ __launch_bounds__(256) void proj_gemm(
    const unsigned short* __restrict__ A, const unsigned short* __restrict__ Bt,
    unsigned short* __restrict__ C, int N, int mode, float scale)
{
  __shared__ __align__(16) unsigned short As[2][4096];
  __shared__ __align__(16) unsigned short Bs[2][4096];
  const int tid = threadIdx.x, lane = tid & 63, w = tid >> 6;
  const int wr = w >> 1, wc = w & 1;
  const int lrow = lane & 15, lg = lane >> 4;
  const size_t bm = (size_t)blockIdx.x * 128;
  const size_t bn = (size_t)blockIdx.y * 128;
  const int rl = lane >> 2, cq = lane & 3;

  auto stage = [&](int kt, int buf) {
#pragma unroll
    for (int u = 0; u < 2; ++u) {
      int row = w * 32 + u * 16 + rl;
      gload16(A  + (bm + row) * 1024 + kt * 32 + cq * 8, &As[buf][(w * 32 + u * 16) * 32]);
      gload16(Bt + (bn + row) * 1024 + kt * 32 + cq * 8, &Bs[buf][(w * 32 + u * 16) * 32]);
    }
  };

  f32x4 acc[4][4] = {};
  stage(0, 0);
  __syncthreads();

  for (int kt = 0; kt < 32; ++kt) {
    const int cur = kt & 1;
    if (kt + 1 < 32) stage(kt + 1, cur ^ 1);
    bf16x8 af[4], bfr[4];
#pragma unroll
    for (int i = 0; i < 4; ++i)
      af[i] = *(const bf16x8*)&As[cur][(wr * 64 + i * 16 + lrow) * 32 + lg * 8];
#pragma unroll
    for (int j = 0; j < 4; ++j)
      bfr[j] = *(const bf16x8*)&Bs[cur][(wc * 64 + j * 16 + lrow) * 32 + lg * 8];
    __builtin_amdgcn_s_setprio(1);
#pragma unroll
    for (int i = 0; i < 4; ++i)
#pragma unroll
      for (int j = 0; j < 4; ++j)
        acc[i][j] = MFMA16(af[i], bfr[j], acc[i][j]);
    __builtin_amdgcn_s_setprio(0);
    __syncthreads();
  }

  const int orow0 = blockIdx.x * 128 + wr * 64;
  const int ocol0 = blockIdx.y * 128 + wc * 64;
  if (mode == 0) {
#pragma unroll
    for (int i = 0; i < 4; ++i)
#pragma unroll
      for (int j = 0; j < 4; ++j) {
        int col = ocol0 + j * 16 + lrow;
#pragma unroll
        for (int r = 0; r < 4; ++r) {
          int row = orow0 + i * 16 + lg * 4 + r;
          C[(size_t)row * N + col] = f2bf(acc[i][j][r] * scale);
        }
      }
  } else {
#pragma unroll
    for (int i = 0; i < 4; ++i) {
      int m0 = orow0 + i * 16 + lg * 4;   // 4 consecutive t within one batch
      int bb = m0 >> 11, t = m0 & 2047;
#pragma unroll
      for (int j = 0; j < 4; ++j) {
        int e = ocol0 + j * 16 + lrow;
        s16x4 pk;
#pragma unroll
        for (int r = 0; r < 4; ++r) pk[r] = (short)f2bf(acc[i][j][r]);
        *(s16x4*)(C + (size_t)bb * 2097152 + (size_t)e * 2048 + t) = pk;
      }
    }
  }
}

// ======================================================================
// 8-phase 256x256 GEMM (BK=64): 8 LDS units (A/B x k-half x dbuf) of 16KB,
// per phase {ds_read frag, stage 1 unit, bar, lgkm0, 16 MFMA, bar},
// vmcnt(8) only at phase 2/4 ends. Unit staged in first phase after its
// previous occupant's last read (A1/B1 at ph1/2, A0/B0 at ph3/4).
// ======================================================================
template<int NT, int NTIL, int MODE>
__global__ __launch_bounds__(512) void gemm8p(
    const unsigned short* __restrict__ Aall, const unsigned short* __restrict__ Ball,
    size_t abatch, size_t bbatch, int lda, int ldb,
    unsigned short* __restrict__ Cb, const float* __restrict__ X,
    float* __restrict__ Out, int b0, int nb)
{
  __shared__ __align__(16) unsigned short lds[65536];  // 128 KB
  const int bid = blockIdx.x;
  const int bloc = bid % nb, tl = bid / nb;
  const int mtile = tl / NTIL, ntile = tl % NTIL;
  const int gb = b0 + bloc;
  const unsigned short* Ag = Aall + (MODE == 0 ? (size_t)gb : (size_t)bloc) * abatch
                                  + (size_t)mtile * 256 * lda;
  const unsigned short* Bg = Ball + (size_t)gb * bbatch + (size_t)ntile * 256 * ldb;

  const int tid = threadIdx.x, lane = tid & 63, w = tid >> 6;
  const int wm = w >> 2, wn = w & 3;
  const int lrow = lane & 15, lg = lane >> 4;
  char* lb = (char*)lds;

  // stage one unit (256 rows x 32 k), pre-swizzled source (rule #21)
  auto stageU = [&](const unsigned short* G, int ld, int kofs, int ubyte) {
#pragma unroll
    for (int i = 0; i < 2; ++i) {
      int c = tid + 512 * i;
      int row = c >> 2, q = c & 3;
      int qs = q ^ ((row >> 1) & 3);
      gload16(G + (size_t)row * ld + kofs + qs * 8, lb + ubyte + c * 16);
    }
  };
  // fragment read with matching swizzle
  auto rdfrag = [&](int ubyte, int row) -> bf16x8 {
    return *(const bf16x8*)(lb + ubyte + row * 64 + ((lg ^ ((row >> 1) & 3)) << 4));
  };

  f32x4 acc[8][4] = {};
  bf16x8 af[8], bfr[2];

  // prologue: A0(0) B0(0) A1(0) B1(0) A0(1) B0(1)  (issue order = steady state)
  stageU(Ag, lda, 0,  (0 * 2 + 0) * 16384);
  stageU(Bg, ldb, 0,  (1 * 2 + 0) * 16384);
  stageU(Ag, lda, 32, (2 * 2 + 0) * 16384);
  stageU(Bg, ldb, 32, (3 * 2 + 0) * 16384);
  stageU(Ag, lda, 64, (0 * 2 + 1) * 16384);
  stageU(Bg, ldb, 64, (1 * 2 + 1) * 16384);
  asm volatile("s_waitcnt vmcnt(8)" ::: "memory");   // A0(0),B0(0) landed
  __builtin_amdgcn_s_barrier();

  for (int T = 0; T < NT; ++T) {
    const int par = T & 1;
    const int a0b = (0 * 2 + par) * 16384, b0b = (1 * 2 + par) * 16384;
    const int a1b = (2 * 2 + par) * 16384, b1b = (3 * 2 + par) * 16384;

    // ---- phase 1: (C-left, k0); stage A1(T+1) ----
#pragma unroll
    for (int mf = 0; mf < 8; ++mf) af[mf] = rdfrag(a0b, wm * 128 + mf * 16 + lrow);
#pragma unroll
    for (int nf = 0; nf < 2; ++nf) bfr[nf] = rdfrag(b0b, wn * 64 + nf * 16 + lrow);
    if (T + 1 < NT) stageU(Ag, lda, (T + 1) * 64 + 32, (2 * 2 + ((T + 1) & 1)) * 16384);
    __builtin_amdgcn_s_barrier();
    asm volatile("s_waitcnt lgkmcnt(0)" ::: "memory");
    __builtin_amdgcn_sched_barrier(0);
    __builtin_amdgcn_s_setprio(1);
#pragma unroll
    for (int mf = 0; mf < 8; ++mf) {
      acc[mf][0] = MFMA16(af[mf], bfr[0], acc[mf][0]);
      acc[mf][1] = MFMA16(af[mf], bfr[1], acc[mf][1]);
    }
    __builtin_amdgcn_s_setprio(0);
    __builtin_amdgcn_s_barrier();

    // ---- phase 2: (C-right, k0); stage B1(T+1); vmcnt ----
#pragma unroll
    for (int nf = 0; nf < 2; ++nf) bfr[nf] = rdfrag(b0b, wn * 64 + (nf + 2) * 16 + lrow);
    if (T + 1 < NT) stageU(Bg, ldb, (T + 1) * 64 + 32, (3 * 2 + ((T + 1) & 1)) * 16384);
    __builtin_amdgcn_s_barrier();
    asm volatile("s_waitcnt lgkmcnt(0)" ::: "memory");
    __builtin_amdgcn_sched_barrier(0);
    __builtin_amdgcn_s_setprio(1);
#pragma unroll
    for (int mf = 0; mf < 8; ++mf) {
      acc[mf][2] = MFMA16(af[mf], bfr[0], acc[mf][2]);
      acc[mf][3] = MFMA16(af[mf], bfr[1], acc[mf][3]);
    }
    __builtin_amdgcn_s_setprio(0);
    asm volatile("s_waitcnt vmcnt(8)" ::: "memory");  // A1(T),B1(T) landed
    __builtin_amdgcn_s_barrier();

    // ---- phase 3: (C-right, k1); stage A0(T+2) ----
#pragma unroll
    for (int mf = 0; mf < 8; ++mf) af[mf] = rdfrag(a1b, wm * 128 + mf * 16 + lrow);
#pragma unroll
    for (int nf = 0; nf < 2; ++nf) bfr[nf] = rdfrag(b1b, wn * 64 + (nf + 2) * 16 + lrow);
    if (T + 2 < NT) stageU(Ag, lda, (T + 2) * 64, (0 * 2 + par) * 16384);
    __builtin_amdgcn_s_barrier();
    asm volatile("s_waitcnt lgkmcnt(0)" ::: "memory");
    __builtin_amdgcn_sched_barrier(0);
    __builtin_amdgcn_s_setprio(1);
#pragma unroll
    for (int mf = 0; mf < 8; ++mf) {
      acc[mf][2] = MFMA16(af[mf], bfr[0], acc[mf][2]);
      acc[mf][3] = MFMA16(af[mf], bfr[1], acc[mf][3]);
    }
    __builtin_amdgcn_s_setprio(0);
    __builtin_amdgcn_s_barrier();

    // ---- phase 4: (C-left, k1); stage B0(T+2); vmcnt ----
#pragma unroll
    for (int nf = 0; nf < 2; ++nf) bfr[nf] = rdfrag(b1b, wn * 64 + nf * 16 + lrow);
    if (T + 2 < NT) stageU(Bg, ldb, (T + 2) * 64, (1 * 2 + par) * 16384);
    __builtin_amdgcn_s_barrier();
    asm volatile("s_waitcnt lgkmcnt(0)" ::: "memory");
    __builtin_amdgcn_sched_barrier(0);
    __builtin_amdgcn_s_setprio(1);
#pragma unroll
    for (int mf = 0; mf < 8; ++mf) {
      acc[mf][0] = MFMA16(af[mf], bfr[0], acc[mf][0]);
      acc[mf][1] = MFMA16(af[mf], bfr[1], acc[mf][1]);
    }
    __builtin_amdgcn_s_setprio(0);
    asm volatile("s_waitcnt vmcnt(8)" ::: "memory");  // A0(T+1),B0(T+1) landed
    __builtin_amdgcn_s_barrier();
  }

  // ---- epilogue ----
  if (MODE == 0) {
    unsigned short* Cp = Cb + (size_t)bloc * 2048 * 2048;
#pragma unroll
    for (int mf = 0; mf < 8; ++mf)
#pragma unroll
      for (int r = 0; r < 4; ++r) {
        int row = mtile * 256 + wm * 128 + mf * 16 + lg * 4 + r;
#pragma unroll
        for (int nf = 0; nf < 4; ++nf) {
          int col = ntile * 256 + wn * 64 + nf * 16 + lrow;
          Cp[(size_t)row * 2048 + col] = f2bf(acc[mf][nf][r]);
        }
      }
  } else {
#pragma unroll
    for (int mf = 0; mf < 8; ++mf)
#pragma unroll
      for (int r = 0; r < 4; ++r) {
        int row = mtile * 256 + wm * 128 + mf * 16 + lg * 4 + r;
        const float* xr = X   + ((size_t)gb * 2048 + row) * 1024;
        float*      orp = Out + ((size_t)gb * 2048 + row) * 1024;
#pragma unroll
        for (int nf = 0; nf < 4; ++nf) {
          int col = ntile * 256 + wn * 64 + nf * 16 + lrow;
          orp[col] = acc[mf][nf][r] + xr[col];
        }
      }
  }
}

// ---- softmax in-place over rows of Sp (normalized P out). 1 wave / row ----
__global__ __launch_bounds__(256) void softmax_kernel(unsigned short* __restrict__ Sp) {
  const int row = blockIdx.x * 4 + (threadIdx.x >> 6);
  const int lane = threadIdx.x & 63;
  unsigned short* rp = Sp + (size_t)row * 2048;
  bf16x8 raw[4];
#pragma unroll
  for (int c = 0; c < 4; ++c) raw[c] = *(const bf16x8*)(rp + c * 512 + lane * 8);
  float v[32];
#pragma unroll
  for (int c = 0; c < 4; ++c)
#pragma unroll
    for (int j = 0; j < 8; ++j) v[c * 8 + j] = bf2f((unsigned short)raw[c][j]);
  float mx = v[0];
#pragma unroll
  for (int j = 1; j < 32; ++j) mx = fmaxf(mx, v[j]);
  mx = fmaxf(mx, __shfl_xor(mx, 1));
  mx = fmaxf(mx, __shfl_xor(mx, 2));
  mx = fmaxf(mx, __shfl_xor(mx, 4));
  mx = fmaxf(mx, __shfl_xor(mx, 8));
  mx = fmaxf(mx, __shfl_xor(mx, 16));
  mx = fmaxf(mx, __shfl_xor(mx, 32));
  float sum = 0.f;
#pragma unroll
  for (int j = 0; j < 32; ++j) { v[j] = __expf(v[j] - mx); sum += v[j]; }
  sum += __shfl_xor(sum, 1);
  sum += __shfl_xor(sum, 2);
  sum += __shfl_xor(sum, 4);
  sum += __shfl_xor(sum, 8);
  sum += __shfl_xor(sum, 16);
  sum += __shfl_xor(sum, 32);
  float inv = 1.0f / sum;
#pragma unroll
  for (int c = 0; c < 4; ++c) {
    bf16x8 pk;
#pragma unroll
    for (int j = 0; j < 8; ++j) pk[j] = (short)f2bf(v[c * 8 + j] * inv);
    *(bf16x8*)(rp + c * 512 + lane * 8) = pk;
  }
}

extern "C" void kernel_launch(void* const* d_in, const int* in_sizes, int n_in,
                              void* d_out, int out_size, void* d_ws, size_t ws_size,
                              hipStream_t stream) {
  (void)in_sizes; (void)n_in; (void)out_size;
  const float* x  = (const float*)d_in[0];
  const float* y  = (const float*)d_in[1];
  const float* Wq = (const float*)d_in[2];
  const float* Wk = (const float*)d_in[3];
  const float* Wv = (const float*)d_in[4];
  float* out = (float*)d_out;

  // bf16 copies of x,y live in d_out during projections (overwritten later)
  unsigned short* xb = (unsigned short*)d_out;
  unsigned short* yb = xb + (size_t)16 * 2048 * 1024;

  // ws (bf16 elems): Wqt | Wkt | Wvt | q | k | Vt | S/P
  unsigned short* Wqt = (unsigned short*)d_ws;
  unsigned short* Wkt = Wqt + (size_t)256 * 1024;
  unsigned short* Wvt = Wkt + (size_t)256 * 1024;
  unsigned short* qws = Wvt + (size_t)1024 * 1024;
  unsigned short* kws = qws + (size_t)16 * 2048 * 256;
  unsigned short* vtw = kws + (size_t)16 * 2048 * 256;
  unsigned short* Sp  = vtw + (size_t)16 * 1024 * 2048;

  const size_t fixed_bytes = (size_t)(Sp - Wqt) * 2;
  const size_t s_batch_bytes = (size_t)2048 * 2048 * 2;
  int nb = 1;
  if      (ws_size >= fixed_bytes + 16 * s_batch_bytes) nb = 16;
  else if (ws_size >= fixed_bytes + 8  * s_batch_bytes) nb = 8;
  else if (ws_size >= fixed_bytes + 4  * s_batch_bytes) nb = 4;
  else if (ws_size >= fixed_bytes + 2  * s_batch_bytes) nb = 2;
  else nb = 1;

  const int n8 = (16 * 2048 * 1024) / 8;
  cvt_bf16<<<2048, 256, 0, stream>>>(x, xb, n8);
  cvt_bf16<<<2048, 256, 0, stream>>>(y, yb, n8);
  tcvt<<<dim3(8, 32),  256, 0, stream>>>(Wq, Wqt, 1024, 256);
  tcvt<<<dim3(8, 32),  256, 0, stream>>>(Wk, Wkt, 1024, 256);
  tcvt<<<dim3(32, 32), 256, 0, stream>>>(Wv, Wvt, 1024, 1024);

  // q scaled by 1/sqrt(OUT_DIM) = 1/32
  proj_gemm<<<dim3(256, 2), 256, 0, stream>>>(xb, Wqt, qws, 256, 0, 0.03125f);
  proj_gemm<<<dim3(256, 2), 256, 0, stream>>>(yb, Wkt, kws, 256, 0, 1.0f);
  proj_gemm<<<dim3(256, 8), 256, 0, stream>>>(yb, Wvt, vtw, 1024, 2, 1.0f);

  for (int b0 = 0; b0 < 16; b0 += nb) {
    // S = q @ k^T  (K=256 -> NT=4, 8 n-tiles)
    gemm8p<4, 8, 0><<<nb * 64, 512, 0, stream>>>(
        qws, kws, (size_t)2048 * 256, (size_t)2048 * 256, 256, 256,
        Sp, nullptr, nullptr, b0, nb);
    softmax_kernel<<<nb * 512, 256, 0, stream>>>(Sp);
    // Out = P @ Vt^T + X  (K=2048 -> NT=32, 4 n-tiles)
    gemm8p<32, 4, 1><<<nb * 32, 512, 0, stream>>>(
        Sp, vtw, (size_t)2048 * 2048, (size_t)1024 * 2048, 2048, 2048,
        nullptr, x, out, b0, nb);
  }
}